// Round 17
// baseline (1102.108 us; speedup 1.0000x reference)
//
#include <hip/hip_runtime.h>
#include <cmath>

typedef __attribute__((ext_vector_type(8))) short bf16x8;
typedef __attribute__((ext_vector_type(4))) float f32x4;

constexpr int N_PTS = 16384;
constexpr int KK    = 30;       // kNN k
constexpr int NEDGE = 262144;
constexpr float NS  = 0.2f;     // leaky relu slope
constexpr int S_SL  = 16;       // pass1 slices
constexpr int M_L   = 8;        // per-bucket approx list size
constexpr int CPQ   = S_SL * 4 * M_L;      // 512 superset candidates/query

__device__ inline short f2bf_rne(float f) {
  unsigned u = __float_as_uint(f);
  unsigned r = (u + 0x7fffu + ((u >> 16) & 1u)) >> 16;
  return (short)r;
}

// parameterized compare-exchange (v_min_u32 + v_max_u32)
#define CEA(a, i, j) { unsigned lo_ = a[i] < a[j] ? a[i] : a[j]; \
                       unsigned hi_ = a[i] < a[j] ? a[j] : a[i]; \
                       a[i] = lo_; a[j] = hi_; }
// Batcher odd-even sort-8 ascending (19 CE)
#define SORT8(a) \
  CEA(a,0,1) CEA(a,2,3) CEA(a,4,5) CEA(a,6,7) \
  CEA(a,0,2) CEA(a,1,3) CEA(a,4,6) CEA(a,5,7) \
  CEA(a,1,2) CEA(a,5,6) \
  CEA(a,0,4) CEA(a,1,5) CEA(a,2,6) CEA(a,3,7) \
  CEA(a,2,4) CEA(a,3,5) \
  CEA(a,1,2) CEA(a,3,4) CEA(a,5,6)
// lowest-8 of (kd ∪ nk), both sorted asc: min vs reversed + 12-CE bitonic sort
#define MERGE8(kd, nk) \
  { _Pragma("unroll") for (int t_ = 0; t_ < 8; ++t_) { \
      unsigned v_ = nk[7 - t_]; kd[t_] = kd[t_] < v_ ? kd[t_] : v_; } } \
  CEA(kd,0,4) CEA(kd,1,5) CEA(kd,2,6) CEA(kd,3,7) \
  CEA(kd,0,2) CEA(kd,1,3) CEA(kd,4,6) CEA(kd,5,7) \
  CEA(kd,0,1) CEA(kd,2,3) CEA(kd,4,5) CEA(kd,6,7)

// compare-exchange on (d, idx) pairs, (d,idx) lexicographic ascending
#define CEP(i, j) { bool c_ = (d[i] < d[j]) || (d[i] == d[j] && id[i] < id[j]); \
  float dl_ = c_ ? d[i] : d[j], dh_ = c_ ? d[j] : d[i]; \
  int   il_ = c_ ? id[i] : id[j], ih_ = c_ ? id[j] : id[i]; \
  d[i] = dl_; d[j] = dh_; id[i] = il_; id[j] = ih_; }
#define SORTP8() \
  CEP(0,1) CEP(2,3) CEP(4,5) CEP(6,7) \
  CEP(0,2) CEP(1,3) CEP(4,6) CEP(5,7) \
  CEP(1,2) CEP(5,6) \
  CEP(0,4) CEP(1,5) CEP(2,6) CEP(3,7) \
  CEP(2,4) CEP(3,5) \
  CEP(1,2) CEP(3,4) CEP(5,6)

// DPP rotation-add within the 16-lane row: x += ror_N(x). VALU-pipe only.
#define ROR_ADD(x, N) \
  { float t_ = __int_as_float(__builtin_amdgcn_update_dpp( \
        0, __float_as_int(x), 0x120 + (N), 0xF, 0xF, 0)); (x) += t_; }

// ---- sq-only for C=3 (conv1 input) -----------------------------------------
__global__ __launch_bounds__(256) void sq3(const float* __restrict__ X,
                                           float* __restrict__ sqv) {
  int p = blockIdx.x * 256 + threadIdx.x;
  float s = 0.f;
#pragma unroll
  for (int c = 0; c < 3; ++c) { float v = X[(size_t)p * 3 + c]; s = fmaf(v, v, s); }
  sqv[p] = s;
}

// ---- Wh1 -> fragment-ordered bf16 hi/lo planes -----------------------------
__global__ __launch_bounds__(256) void wh1prep(const float* __restrict__ Wh1,
    short* __restrict__ whH, short* __restrict__ whL) {
  for (int i = threadIdx.x; i < 1024; i += 256) {
    int lane = i & 63, ktct = i >> 6;
    int kt = ktct & 3, ct = ktct >> 2;
    int colw = lane & 15, quadw = lane >> 4;
#pragma unroll
    for (int j = 0; j < 8; ++j) {
      float v = Wh1[(size_t)(kt * 32 + quadw * 8 + j) * 64 + ct * 16 + colw];
      short h = f2bf_rne(v);
      float hf = __uint_as_float(((unsigned)(unsigned short)h) << 16);
      whH[(size_t)i * 8 + j] = h;
      whL[(size_t)i * 8 + j] = f2bf_rne(v - hf);
    }
  }
}

// ---- C=3 pass1: direct fp32 scan, thread-per-query -------------------------
__global__ __launch_bounds__(256) void knn_scan3(
    const float* __restrict__ X, const float* __restrict__ sqv,
    unsigned short* __restrict__ cand) {
  const int q = blockIdx.x * 256 + threadIdx.x;
  const int slice = blockIdx.y;
  const int c0 = slice * 1024;
  const float x0 = X[(size_t)q * 3 + 0];
  const float x1 = X[(size_t)q * 3 + 1];
  const float x2 = X[(size_t)q * 3 + 2];

  unsigned kq0[8], kq1[8], kq2[8], kq3[8];
#pragma unroll
  for (int t = 0; t < 8; ++t) { kq0[t]=0xFFFFFFFFu; kq1[t]=0xFFFFFFFFu;
                                kq2[t]=0xFFFFFFFFu; kq3[t]=0xFFFFFFFFu; }

#define SCAN_QTR(kd, QO) \
  for (int t = 0; t < 256; t += 8) { \
    unsigned nk[8]; \
    _Pragma("unroll") for (int u = 0; u < 8; ++u) { \
      const int j = c0 + (QO) * 256 + t + u; \
      float dj = fmaf(x0, X[(size_t)j*3+0], fmaf(x1, X[(size_t)j*3+1], x2 * X[(size_t)j*3+2])); \
      float key = fmaf(dj, -2.f, sqv[j]); \
      unsigned uu = __float_as_uint(key); \
      uu ^= ((unsigned)((int)uu >> 31)) | 0x80000000u; \
      nk[u] = (uu & 0xFFFFFF00u) | (unsigned)(t + u); \
    } \
    SORT8(nk) MERGE8(kd, nk) \
  }
  SCAN_QTR(kq0, 0)
  SCAN_QTR(kq1, 1)
  SCAN_QTR(kq2, 2)
  SCAN_QTR(kq3, 3)
#undef SCAN_QTR

  unsigned short* o = cand + (size_t)q * CPQ + slice * 32;
#pragma unroll
  for (int t = 0; t < 8; ++t) {
    o[t]      = (unsigned short)(c0 +   0 + (int)(kq0[t] & 0xFFu));
    o[8 + t]  = (unsigned short)(c0 + 256 + (int)(kq1[t] & 0xFFu));
    o[16 + t] = (unsigned short)(c0 + 512 + (int)(kq2[t] & 0xFFu));
    o[24 + t] = (unsigned short)(c0 + 768 + (int)(kq3[t] & 0xFFu));
  }
}

// ---- C=64 pass1: bf16 MFMA approx distances, 4 query-groups/wave -----------
// Modulo-2 software pipeline: A-tiles for batch t+1 prefetched before batch
// t's ~880-cycle sort/merge VALU block (forces load hoisting under pressure).
template<int KT>
__global__ __launch_bounds__(256) void knn_pass1(
    const short* __restrict__ Xh, const float* __restrict__ sqv,
    unsigned short* __restrict__ cand) {
  constexpr int CP = KT * 32;
  const int tid  = threadIdx.x;
  const int lane = tid & 63;
  const int wv   = tid >> 6;
  const int col  = lane & 15;
  const int quad = lane >> 4;
  const int qb   = blockIdx.x * 256 + wv * 64 + col;
  const int slice = blockIdx.y;
  const int slen = N_PTS / S_SL;  // 1024
  const int c0 = slice * slen;

  bf16x8 bq[4][KT];
#pragma unroll
  for (int g = 0; g < 4; ++g)
#pragma unroll
    for (int kt = 0; kt < KT; ++kt)
      bq[g][kt] = *(const bf16x8*)(Xh + (size_t)(qb + g * 16) * CP + kt * 32 + quad * 8);

  unsigned kd0[M_L], kd1[M_L], kd2[M_L], kd3[M_L];
#pragma unroll
  for (int t = 0; t < M_L; ++t) {
    kd0[t] = 0xFFFFFFFFu; kd1[t] = 0xFFFFFFFFu;
    kd2[t] = 0xFFFFFFFFu; kd3[t] = 0xFFFFFFFFu;
  }

  const int NB = slen / 32;   // 32, even

  auto loadA = [&](bf16x8 (&t0)[KT], bf16x8 (&t1)[KT], int bt) {
    const int cb = c0 + bt * 32;
    const size_t arow0 = (size_t)(cb + col) * CP + quad * 8;
    const size_t arow1 = arow0 + (size_t)16 * CP;
#pragma unroll
    for (int kt = 0; kt < KT; ++kt) {
      t0[kt] = *(const bf16x8*)(Xh + arow0 + kt * 32);
      t1[kt] = *(const bf16x8*)(Xh + arow1 + kt * 32);
    }
  };

  auto computeB = [&](const bf16x8 (&t0)[KT], const bf16x8 (&t1)[KT], int bt) {
    const int cb = c0 + bt * 32;
    unsigned nk0[8], nk1[8], nk2[8], nk3[8];
    {
      f32x4 a0 = {0.f,0.f,0.f,0.f}, a1 = {0.f,0.f,0.f,0.f};
      f32x4 a2 = {0.f,0.f,0.f,0.f}, a3 = {0.f,0.f,0.f,0.f};
#pragma unroll
      for (int kt = 0; kt < KT; ++kt) {
        a0 = __builtin_amdgcn_mfma_f32_16x16x32_bf16(t0[kt], bq[0][kt], a0, 0, 0, 0);
        a1 = __builtin_amdgcn_mfma_f32_16x16x32_bf16(t0[kt], bq[1][kt], a1, 0, 0, 0);
        a2 = __builtin_amdgcn_mfma_f32_16x16x32_bf16(t0[kt], bq[2][kt], a2, 0, 0, 0);
        a3 = __builtin_amdgcn_mfma_f32_16x16x32_bf16(t0[kt], bq[3][kt], a3, 0, 0, 0);
      }
      f32x4 sc = *(const f32x4*)(sqv + cb + quad * 4);
      const unsigned lb = (unsigned)bt * 8;
#pragma unroll
      for (int r = 0; r < 4; ++r) {
        unsigned u0 = __float_as_uint(fmaf(a0[r], -2.f, sc[r]));
        unsigned u1 = __float_as_uint(fmaf(a1[r], -2.f, sc[r]));
        unsigned u2 = __float_as_uint(fmaf(a2[r], -2.f, sc[r]));
        unsigned u3 = __float_as_uint(fmaf(a3[r], -2.f, sc[r]));
        u0 ^= ((unsigned)((int)u0 >> 31)) | 0x80000000u;
        u1 ^= ((unsigned)((int)u1 >> 31)) | 0x80000000u;
        u2 ^= ((unsigned)((int)u2 >> 31)) | 0x80000000u;
        u3 ^= ((unsigned)((int)u3 >> 31)) | 0x80000000u;
        nk0[r] = (u0 & 0xFFFFFF00u) | (lb + r);
        nk1[r] = (u1 & 0xFFFFFF00u) | (lb + r);
        nk2[r] = (u2 & 0xFFFFFF00u) | (lb + r);
        nk3[r] = (u3 & 0xFFFFFF00u) | (lb + r);
      }
    }
    {
      f32x4 a0 = {0.f,0.f,0.f,0.f}, a1 = {0.f,0.f,0.f,0.f};
      f32x4 a2 = {0.f,0.f,0.f,0.f}, a3 = {0.f,0.f,0.f,0.f};
#pragma unroll
      for (int kt = 0; kt < KT; ++kt) {
        a0 = __builtin_amdgcn_mfma_f32_16x16x32_bf16(t1[kt], bq[0][kt], a0, 0, 0, 0);
        a1 = __builtin_amdgcn_mfma_f32_16x16x32_bf16(t1[kt], bq[1][kt], a1, 0, 0, 0);
        a2 = __builtin_amdgcn_mfma_f32_16x16x32_bf16(t1[kt], bq[2][kt], a2, 0, 0, 0);
        a3 = __builtin_amdgcn_mfma_f32_16x16x32_bf16(t1[kt], bq[3][kt], a3, 0, 0, 0);
      }
      f32x4 sc = *(const f32x4*)(sqv + cb + 16 + quad * 4);
      const unsigned lb = (unsigned)bt * 8 + 4;
#pragma unroll
      for (int r = 0; r < 4; ++r) {
        unsigned u0 = __float_as_uint(fmaf(a0[r], -2.f, sc[r]));
        unsigned u1 = __float_as_uint(fmaf(a1[r], -2.f, sc[r]));
        unsigned u2 = __float_as_uint(fmaf(a2[r], -2.f, sc[r]));
        unsigned u3 = __float_as_uint(fmaf(a3[r], -2.f, sc[r]));
        u0 ^= ((unsigned)((int)u0 >> 31)) | 0x80000000u;
        u1 ^= ((unsigned)((int)u1 >> 31)) | 0x80000000u;
        u2 ^= ((unsigned)((int)u2 >> 31)) | 0x80000000u;
        u3 ^= ((unsigned)((int)u3 >> 31)) | 0x80000000u;
        nk0[4 + r] = (u0 & 0xFFFFFF00u) | (lb + r);
        nk1[4 + r] = (u1 & 0xFFFFFF00u) | (lb + r);
        nk2[4 + r] = (u2 & 0xFFFFFF00u) | (lb + r);
        nk3[4 + r] = (u3 & 0xFFFFFF00u) | (lb + r);
      }
    }
    SORT8(nk0) MERGE8(kd0, nk0)
    SORT8(nk1) MERGE8(kd1, nk1)
    SORT8(nk2) MERGE8(kd2, nk2)
    SORT8(nk3) MERGE8(kd3, nk3)
  };

  bf16x8 aA0[KT], aA1[KT], aB0[KT], aB1[KT];
  loadA(aA0, aA1, 0);
  for (int bt = 0; bt < NB; bt += 2) {
    loadA(aB0, aB1, bt + 1);
    computeB(aA0, aA1, bt);
    loadA(aA0, aA1, (bt + 2 < NB) ? bt + 2 : 0);
    computeB(aB0, aB1, bt + 1);
  }

#pragma unroll
  for (int g = 0; g < 4; ++g) {
    const unsigned* kd = (g == 0) ? kd0 : (g == 1) ? kd1 : (g == 2) ? kd2 : kd3;
    unsigned short* o =
        cand + ((size_t)(qb + g * 16) * S_SL + slice) * (4 * M_L) + quad * M_L;
#pragma unroll
    for (int t = 0; t < M_L; ++t) {
      unsigned l = kd[t] & 0xFFu;
      o[t] = (unsigned short)(c0 + (int)(l >> 2) * 16 + quad * 4 + (int)(l & 3));
    }
  }
}

// ---- pass 2 v2 (C=64): LDS-staged gather (32-cand batches) + DPP reduce ----
__global__ __launch_bounds__(256) void knn_pass2v2(
    const float* __restrict__ X, const float* __restrict__ sqv,
    const unsigned short* __restrict__ cand, int* __restrict__ knn) {
  __shared__ int   ldsC[4][CPQ];
  __shared__ float ldsD[4][CPQ];
  const int lane = threadIdx.x & 63, wv = threadIdx.x >> 6;
  const int q = blockIdx.x * 4 + wv;
  const int s = lane & 15;
  const int g = lane >> 4;
  const float sqq = sqv[q];
  constexpr int PL = CPQ / 64;   // 8

#pragma unroll
  for (int u = 0; u < PL; ++u)
    ldsC[wv][u * 64 + lane] = (int)cand[(size_t)q * CPQ + u * 64 + lane];
  f32x4 xq = *(const f32x4*)(X + (size_t)q * 64 + s * 4);
  __syncthreads();

  for (int it = 0; it < CPQ / 32; ++it) {   // 16 iters x 32 candidates
    int jj[8];
#pragma unroll
    for (int uu = 0; uu < 8; ++uu) jj[uu] = ldsC[wv][it * 32 + uu * 4 + g];
    f32x4 vv[8];
#pragma unroll
    for (int uu = 0; uu < 8; ++uu)
      vv[uu] = *(const f32x4*)(X + (size_t)jj[uu] * 64 + s * 4);
    float sj[8];
#pragma unroll
    for (int uu = 0; uu < 8; ++uu) sj[uu] = sqv[jj[uu]];
#pragma unroll
    for (int uu = 0; uu < 8; ++uu) {
      float p = fmaf(xq[0], vv[uu][0], fmaf(xq[1], vv[uu][1],
                fmaf(xq[2], vv[uu][2], xq[3] * vv[uu][3])));
      ROR_ADD(p, 8) ROR_ADD(p, 4) ROR_ADD(p, 2) ROR_ADD(p, 1)
      if (s == 0) ldsD[wv][it * 32 + uu * 4 + g] = (sqq + sj[uu]) - 2.f * p;
    }
  }
  __syncthreads();

  float d[PL]; int id[PL];
#pragma unroll
  for (int u = 0; u < PL; ++u) {
    d[u]  = ldsD[wv][u * 64 + lane];
    id[u] = ldsC[wv][u * 64 + lane];
  }
  SORTP8();
  for (int r = 0; r < KK; ++r) {
    float bd = d[0]; int bi = id[0];
#pragma unroll
    for (int off = 32; off; off >>= 1) {
      float od = __shfl_xor(bd, off, 64);
      int   oi = __shfl_xor(bi, off, 64);
      bool c = (od < bd) || (od == bd && oi < bi);
      bd = c ? od : bd; bi = c ? oi : bi;
    }
    if (lane == 0) knn[(size_t)q * KK + r] = bi;
    bool win = (d[0] == bd) && (id[0] == bi);
#pragma unroll
    for (int t = 0; t < PL - 1; ++t) {
      d[t]  = win ? d[t + 1]  : d[t];
      id[t] = win ? id[t + 1] : id[t];
    }
    d[PL - 1] = win ? __builtin_inff() : d[PL - 1];
  }
}

// ---- pass 2 (coalesced, C=3 path) ------------------------------------------
template<int C, int GRP, int LG>
__global__ __launch_bounds__(256) void knn_pass2co(
    const float* __restrict__ X, const float* __restrict__ sqv,
    const unsigned short* __restrict__ cand, int* __restrict__ knn) {
  __shared__ float ldsD[4][CPQ];
  const int lane = threadIdx.x & 63, wv = threadIdx.x >> 6;
  const int q = blockIdx.x * 4 + wv;
  const int s = lane & (GRP - 1);
  const int g = lane >> LG;
  constexpr int RPI = 64 / GRP;
  constexpr int NIT = CPQ / RPI;
  const float sqq = sqv[q];

  float xqv[4];
  if constexpr (GRP == 16) {
#pragma unroll
    for (int u = 0; u < 4; ++u) xqv[u] = X[(size_t)q * C + s * 4 + u];
  } else {
    xqv[0] = (s < C) ? X[(size_t)q * C + s] : 0.f;
  }

  for (int it = 0; it < NIT; ++it) {
    const int t = it * RPI + g;
    const int j = (int)cand[(size_t)q * CPQ + t];
    float p;
    if constexpr (GRP == 16) {
      f32x4 v = *(const f32x4*)(X + (size_t)j * C + s * 4);
      p = fmaf(xqv[0], v[0], fmaf(xqv[1], v[1], fmaf(xqv[2], v[2], xqv[3] * v[3])));
    } else {
      float v = (s < C) ? X[(size_t)j * C + s] : 0.f;
      p = xqv[0] * v;
    }
#pragma unroll
    for (int off = 1; off < GRP; off <<= 1) p += __shfl_xor(p, off, 64);
    if (s == 0) ldsD[wv][t] = (sqq + sqv[j]) - 2.f * p;
  }
  __syncthreads();

  constexpr int PL = CPQ / 64;
  float d[PL]; int id[PL];
#pragma unroll
  for (int u = 0; u < PL; ++u) {
    d[u]  = ldsD[wv][u * 64 + lane];
    id[u] = (int)cand[(size_t)q * CPQ + u * 64 + lane];
  }
  for (int r = 0; r < KK; ++r) {
    float bd = d[0]; int bi = id[0];
#pragma unroll
    for (int u = 1; u < PL; ++u) {
      bool c = (d[u] < bd) || (d[u] == bd && id[u] < bi);
      bd = c ? d[u] : bd; bi = c ? id[u] : bi;
    }
#pragma unroll
    for (int off = 32; off; off >>= 1) {
      float od = __shfl_xor(bd, off, 64);
      int   oi = __shfl_xor(bi, off, 64);
      bool c = (od < bd) || (od == bd && oi < bi);
      bd = c ? od : bd; bi = c ? oi : bi;
    }
    if (lane == 0) knn[(size_t)q * KK + r] = bi;
#pragma unroll
    for (int u = 0; u < PL; ++u) if (id[u] == bi) d[u] = __builtin_inff();
  }
}

// ---- DynamicEdgeConv with fused epilogues ----------------------------------
template<int C, int PPW, int EPI>
__global__ __launch_bounds__(256) void edge_conv(
    const float* __restrict__ X, const int* __restrict__ knn,
    const float* __restrict__ W, const float* __restrict__ B,
    float* __restrict__ Y, float* __restrict__ sqv,
    short* __restrict__ Xh, short* __restrict__ Xl) {
  const int wv = __builtin_amdgcn_readfirstlane(threadIdx.x >> 6);
  const int lane = threadIdx.x & 63;
  float wd[C], wj[C];
#pragma unroll
  for (int c = 0; c < C; ++c) {
    float w0 = W[c * 64 + lane];
    float w1 = W[(C + c) * 64 + lane];
    wd[c] = w0 - w1; wj[c] = w1;
  }
  const float bb = B[lane];
  const int p0 = (blockIdx.x * 4 + wv) * PPW;
  for (int pp = 0; pp < PPW; ++pp) {
    const int p = p0 + pp;
    const float* __restrict__ xi = X + (size_t)p * C;
    float base = bb;
#pragma unroll
    for (int c = 0; c < C; ++c) base = fmaf(xi[c], wd[c], base);
    float m = -__builtin_inff();
    for (int n = 0; n < KK; ++n) {
      const int j = __builtin_amdgcn_readfirstlane(knn[(size_t)p * KK + n]);
      const float* __restrict__ xj = X + (size_t)j * C;
      float acc;
      if constexpr (C % 4 == 0) {
        float a0 = 0.f, a1 = 0.f, a2 = 0.f, a3 = 0.f;
#pragma unroll
        for (int c = 0; c < C; c += 4) {
          a0 = fmaf(xj[c + 0], wj[c + 0], a0);
          a1 = fmaf(xj[c + 1], wj[c + 1], a1);
          a2 = fmaf(xj[c + 2], wj[c + 2], a2);
          a3 = fmaf(xj[c + 3], wj[c + 3], a3);
        }
        acc = base + ((a0 + a1) + (a2 + a3));
      } else {
        acc = base;
#pragma unroll
        for (int c = 0; c < C; ++c) acc = fmaf(xj[c], wj[c], acc);
      }
      acc = acc > 0.f ? acc : NS * acc;
      m = fmaxf(m, acc);
    }
    if constexpr (EPI == 1) {
      Y[(size_t)p * 64 + lane] = m;
      Xh[(size_t)p * 64 + lane] = f2bf_rne(m);
      float s = m * m;
#pragma unroll
      for (int off = 32; off; off >>= 1) s += __shfl_xor(s, off, 64);
      if (lane == 0) sqv[p] = s;
    } else {
      short h = f2bf_rne(m);
      float hf = __uint_as_float(((unsigned)(unsigned short)h) << 16);
      Xh[(size_t)p * 64 + lane] = h;
      Xl[(size_t)p * 64 + lane] = f2bf_rne(m - hf);
    }
  }
}

// ---- edge head via hi/lo bf16 MFMA -----------------------------------------
template<int ET>
__global__ __launch_bounds__(256) void edge_head_mfma(
    const short* __restrict__ Xh, const short* __restrict__ Xl,
    const int* __restrict__ ei,
    const short* __restrict__ whH, const short* __restrict__ whL,
    const float* __restrict__ bh1, const float* __restrict__ Wh2,
    const float* __restrict__ bh2, float* __restrict__ out) {
  const int lane = threadIdx.x & 63, wv = threadIdx.x >> 6;
  const int col = lane & 15, quad = lane >> 4;

  bf16x8 bh[4][4], bl[4][4];   // [ct][kt]
#pragma unroll
  for (int ct = 0; ct < 4; ++ct)
#pragma unroll
    for (int kt = 0; kt < 4; ++kt) {
      const size_t idx = ((size_t)(ct * 4 + kt) * 64 + lane) * 8;
      bh[ct][kt] = *(const bf16x8*)(whH + idx);
      bl[ct][kt] = *(const bf16x8*)(whL + idx);
    }
  float bb[4], w2[4];
#pragma unroll
  for (int ct = 0; ct < 4; ++ct) {
    bb[ct] = bh1[ct * 16 + col];
    w2[ct] = Wh2[ct * 16 + col];
  }
  const float b2 = bh2[0];

  const int t0 = (blockIdx.x * 4 + wv) * ET;
  for (int tt = 0; tt < ET; ++tt) {
    const int e = (t0 + tt) * 16 + col;
    const int a = ei[e], b = ei[NEDGE + e];
    const int v0 = min(a, b), v1 = max(a, b);
    bf16x8 ah[4], al[4];
#pragma unroll
    for (int kt = 0; kt < 4; ++kt) {
      const int row = (kt < 2) ? v0 : v1;
      const size_t off = (size_t)row * 64 + (kt & 1) * 32 + quad * 8;
      ah[kt] = *(const bf16x8*)(Xh + off);
      al[kt] = *(const bf16x8*)(Xl + off);
    }
    f32x4 acc[4];
#pragma unroll
    for (int ct = 0; ct < 4; ++ct) acc[ct] = f32x4{0.f, 0.f, 0.f, 0.f};
#pragma unroll
    for (int kt = 0; kt < 4; ++kt)
#pragma unroll
      for (int ct = 0; ct < 4; ++ct) {
        acc[ct] = __builtin_amdgcn_mfma_f32_16x16x32_bf16(ah[kt], bh[ct][kt], acc[ct], 0, 0, 0);
        acc[ct] = __builtin_amdgcn_mfma_f32_16x16x32_bf16(ah[kt], bl[ct][kt], acc[ct], 0, 0, 0);
        acc[ct] = __builtin_amdgcn_mfma_f32_16x16x32_bf16(al[kt], bh[ct][kt], acc[ct], 0, 0, 0);
      }
    float z[4];
#pragma unroll
    for (int r = 0; r < 4; ++r) {
      float zz = 0.f;
#pragma unroll
      for (int ct = 0; ct < 4; ++ct) {
        float h = acc[ct][r] + bb[ct];
        h = h > 0.f ? h : NS * h;
        zz = fmaf(h, w2[ct], zz);
      }
      ROR_ADD(zz, 8) ROR_ADD(zz, 4) ROR_ADD(zz, 2) ROR_ADD(zz, 1)
      z[r] = zz;
    }
    if (col == 0) {
#pragma unroll
      for (int r = 0; r < 4; ++r)
        out[(t0 + tt) * 16 + quad * 4 + r] = 1.f / (1.f + expf(-(z[r] + b2)));
    }
  }
}

// -----------------------------------------------------------------------------
extern "C" void kernel_launch(void* const* d_in, const int* in_sizes, int n_in,
                              void* d_out, int out_size, void* d_ws, size_t ws_size,
                              hipStream_t stream) {
  const float* x   = (const float*)d_in[0];
  const int*   ei  = (const int*)d_in[1];
  const float* W1  = (const float*)d_in[2];
  const float* b1  = (const float*)d_in[3];
  const float* W2  = (const float*)d_in[4];
  const float* b2  = (const float*)d_in[5];
  const float* W3  = (const float*)d_in[6];
  const float* b3  = (const float*)d_in[7];
  const float* Wh1 = (const float*)d_in[8];
  const float* bh1 = (const float*)d_in[9];
  const float* Wh2 = (const float*)d_in[10];
  const float* bh2 = (const float*)d_in[11];
  float* out = (float*)d_out;

  char* ws = (char*)d_ws;
  float* xA  = (float*)ws; ws += (size_t)N_PTS * 64 * 4;      // 4 MB
  float* xB  = (float*)ws; ws += (size_t)N_PTS * 64 * 4;      // 4 MB
  float* sqb = (float*)ws; ws += (size_t)N_PTS * 4;
  int*   knn = (int*)ws;   ws += (size_t)N_PTS * KK * 4;      // 1.9 MB
  short* Xh  = (short*)ws; ws += (size_t)N_PTS * 64 * 2;      // 2 MB
  short* Xl  = (short*)ws; ws += (size_t)N_PTS * 64 * 2;      // 2 MB
  short* whH = (short*)ws; ws += (size_t)8192 * 2;            // 16 KB
  short* whL = (short*)ws; ws += (size_t)8192 * 2;            // 16 KB
  unsigned short* cand = (unsigned short*)ws;
  ws += (size_t)N_PTS * CPQ * 2;                              // 16.7 MB
  (void)ws_size; (void)in_sizes; (void)n_in; (void)out_size;

  wh1prep<<<1, 256, 0, stream>>>(Wh1, whH, whL);

  // ---- conv1 (C=3): direct fp32 scan; edge_conv fuses sq+bf16hi of xA ----
  sq3<<<N_PTS / 256, 256, 0, stream>>>(x, sqb);
  knn_scan3<<<dim3(N_PTS / 256, S_SL), 256, 0, stream>>>(x, sqb, cand);
  knn_pass2co<3, 4, 2><<<N_PTS / 4, 256, 0, stream>>>(x, sqb, cand, knn);
  edge_conv<3, 4, 1><<<N_PTS / 16, 256, 0, stream>>>(x, knn, W1, b1, xA, sqb, Xh, Xl);
  // ---- conv2 (C=64): edge_conv fuses sq+bf16hi of xB ----
  knn_pass1<2><<<dim3(N_PTS / 256, S_SL), 256, 0, stream>>>(Xh, sqb, cand);
  knn_pass2v2<<<N_PTS / 4, 256, 0, stream>>>(xA, sqb, cand, knn);
  edge_conv<64, 4, 1><<<N_PTS / 16, 256, 0, stream>>>(xA, knn, W2, b2, xB, sqb, Xh, Xl);
  // ---- conv3 (C=64): edge_conv emits hi/lo planes only (no Y) ----
  knn_pass1<2><<<dim3(N_PTS / 256, S_SL), 256, 0, stream>>>(Xh, sqb, cand);
  knn_pass2v2<<<N_PTS / 4, 256, 0, stream>>>(xB, sqb, cand, knn);
  edge_conv<64, 4, 2><<<N_PTS / 16, 256, 0, stream>>>(xB, knn, W3, b3, nullptr, nullptr, Xh, Xl);
  // ---- edge head: MFMA on hi/lo planes ----
  edge_head_mfma<8><<<NEDGE / (16 * 4 * 8), 256, 0, stream>>>(
      Xh, Xl, ei, whH, whL, bh1, Wh2, bh2, out);
}

// Round 18
// 1067.292 us; speedup vs baseline: 1.0326x; 1.0326x over previous
//
#include <hip/hip_runtime.h>
#include <cmath>

typedef __attribute__((ext_vector_type(8))) short bf16x8;
typedef __attribute__((ext_vector_type(4))) float f32x4;

constexpr int N_PTS = 16384;
constexpr int KK    = 30;       // kNN k
constexpr int NEDGE = 262144;
constexpr float NS  = 0.2f;     // leaky relu slope
constexpr int S_SL  = 16;       // pass1 slices
constexpr int M_L   = 8;        // per-bucket approx list size
constexpr int CPQ   = S_SL * 4 * M_L;      // 512 superset candidates/query

__device__ inline short f2bf_rne(float f) {
  unsigned u = __float_as_uint(f);
  unsigned r = (u + 0x7fffu + ((u >> 16) & 1u)) >> 16;
  return (short)r;
}

// parameterized compare-exchange (v_min_u32 + v_max_u32)
#define CEA(a, i, j) { unsigned lo_ = a[i] < a[j] ? a[i] : a[j]; \
                       unsigned hi_ = a[i] < a[j] ? a[j] : a[i]; \
                       a[i] = lo_; a[j] = hi_; }
// Batcher odd-even sort-8 ascending (19 CE)
#define SORT8(a) \
  CEA(a,0,1) CEA(a,2,3) CEA(a,4,5) CEA(a,6,7) \
  CEA(a,0,2) CEA(a,1,3) CEA(a,4,6) CEA(a,5,7) \
  CEA(a,1,2) CEA(a,5,6) \
  CEA(a,0,4) CEA(a,1,5) CEA(a,2,6) CEA(a,3,7) \
  CEA(a,2,4) CEA(a,3,5) \
  CEA(a,1,2) CEA(a,3,4) CEA(a,5,6)
// lowest-8 of (kd ∪ nk), both sorted asc: min vs reversed + 12-CE bitonic sort
#define MERGE8(kd, nk) \
  { _Pragma("unroll") for (int t_ = 0; t_ < 8; ++t_) { \
      unsigned v_ = nk[7 - t_]; kd[t_] = kd[t_] < v_ ? kd[t_] : v_; } } \
  CEA(kd,0,4) CEA(kd,1,5) CEA(kd,2,6) CEA(kd,3,7) \
  CEA(kd,0,2) CEA(kd,1,3) CEA(kd,4,6) CEA(kd,5,7) \
  CEA(kd,0,1) CEA(kd,2,3) CEA(kd,4,5) CEA(kd,6,7)

// compare-exchange on (d, idx) pairs, (d,idx) lexicographic ascending
#define CEP(i, j) { bool c_ = (d[i] < d[j]) || (d[i] == d[j] && id[i] < id[j]); \
  float dl_ = c_ ? d[i] : d[j], dh_ = c_ ? d[j] : d[i]; \
  int   il_ = c_ ? id[i] : id[j], ih_ = c_ ? id[j] : id[i]; \
  d[i] = dl_; d[j] = dh_; id[i] = il_; id[j] = ih_; }
#define SORTP8() \
  CEP(0,1) CEP(2,3) CEP(4,5) CEP(6,7) \
  CEP(0,2) CEP(1,3) CEP(4,6) CEP(5,7) \
  CEP(1,2) CEP(5,6) \
  CEP(0,4) CEP(1,5) CEP(2,6) CEP(3,7) \
  CEP(2,4) CEP(3,5) \
  CEP(1,2) CEP(3,4) CEP(5,6)

// DPP rotation-add within the 16-lane row: x += ror_N(x). VALU-pipe only.
#define ROR_ADD(x, N) \
  { float t_ = __int_as_float(__builtin_amdgcn_update_dpp( \
        0, __float_as_int(x), 0x120 + (N), 0xF, 0xF, 0)); (x) += t_; }

// ---- sq-only for C=3 (conv1 input) -----------------------------------------
__global__ __launch_bounds__(256) void sq3(const float* __restrict__ X,
                                           float* __restrict__ sqv) {
  int p = blockIdx.x * 256 + threadIdx.x;
  float s = 0.f;
#pragma unroll
  for (int c = 0; c < 3; ++c) { float v = X[(size_t)p * 3 + c]; s = fmaf(v, v, s); }
  sqv[p] = s;
}

// ---- Wh1 -> fragment-ordered bf16 hi/lo planes -----------------------------
__global__ __launch_bounds__(256) void wh1prep(const float* __restrict__ Wh1,
    short* __restrict__ whH, short* __restrict__ whL) {
  for (int i = threadIdx.x; i < 1024; i += 256) {
    int lane = i & 63, ktct = i >> 6;
    int kt = ktct & 3, ct = ktct >> 2;
    int colw = lane & 15, quadw = lane >> 4;
#pragma unroll
    for (int j = 0; j < 8; ++j) {
      float v = Wh1[(size_t)(kt * 32 + quadw * 8 + j) * 64 + ct * 16 + colw];
      short h = f2bf_rne(v);
      float hf = __uint_as_float(((unsigned)(unsigned short)h) << 16);
      whH[(size_t)i * 8 + j] = h;
      whL[(size_t)i * 8 + j] = f2bf_rne(v - hf);
    }
  }
}

// ---- C=3 pass1: direct fp32 scan, thread-per-query -------------------------
__global__ __launch_bounds__(256) void knn_scan3(
    const float* __restrict__ X, const float* __restrict__ sqv,
    unsigned short* __restrict__ cand) {
  const int q = blockIdx.x * 256 + threadIdx.x;
  const int slice = blockIdx.y;
  const int c0 = slice * 1024;
  const float x0 = X[(size_t)q * 3 + 0];
  const float x1 = X[(size_t)q * 3 + 1];
  const float x2 = X[(size_t)q * 3 + 2];

  unsigned kq0[8], kq1[8], kq2[8], kq3[8];
#pragma unroll
  for (int t = 0; t < 8; ++t) { kq0[t]=0xFFFFFFFFu; kq1[t]=0xFFFFFFFFu;
                                kq2[t]=0xFFFFFFFFu; kq3[t]=0xFFFFFFFFu; }

#define SCAN_QTR(kd, QO) \
  for (int t = 0; t < 256; t += 8) { \
    unsigned nk[8]; \
    _Pragma("unroll") for (int u = 0; u < 8; ++u) { \
      const int j = c0 + (QO) * 256 + t + u; \
      float dj = fmaf(x0, X[(size_t)j*3+0], fmaf(x1, X[(size_t)j*3+1], x2 * X[(size_t)j*3+2])); \
      float key = fmaf(dj, -2.f, sqv[j]); \
      unsigned uu = __float_as_uint(key); \
      uu ^= ((unsigned)((int)uu >> 31)) | 0x80000000u; \
      nk[u] = (uu & 0xFFFFFF00u) | (unsigned)(t + u); \
    } \
    SORT8(nk) MERGE8(kd, nk) \
  }
  SCAN_QTR(kq0, 0)
  SCAN_QTR(kq1, 1)
  SCAN_QTR(kq2, 2)
  SCAN_QTR(kq3, 3)
#undef SCAN_QTR

  unsigned short* o = cand + (size_t)q * CPQ + slice * 32;
#pragma unroll
  for (int t = 0; t < 8; ++t) {
    o[t]      = (unsigned short)(c0 +   0 + (int)(kq0[t] & 0xFFu));
    o[8 + t]  = (unsigned short)(c0 + 256 + (int)(kq1[t] & 0xFFu));
    o[16 + t] = (unsigned short)(c0 + 512 + (int)(kq2[t] & 0xFFu));
    o[24 + t] = (unsigned short)(c0 + 768 + (int)(kq3[t] & 0xFFu));
  }
}

// ---- C=64 pass1: bf16 MFMA approx distances, 4 query-groups/wave -----------
// (R16 version — no explicit pipeline; compiler schedule + occupancy win)
template<int KT>
__global__ __launch_bounds__(256) void knn_pass1(
    const short* __restrict__ Xh, const float* __restrict__ sqv,
    unsigned short* __restrict__ cand) {
  constexpr int CP = KT * 32;
  const int tid  = threadIdx.x;
  const int lane = tid & 63;
  const int wv   = tid >> 6;
  const int col  = lane & 15;
  const int quad = lane >> 4;
  const int qb   = blockIdx.x * 256 + wv * 64 + col;
  const int slice = blockIdx.y;
  const int slen = N_PTS / S_SL;  // 1024
  const int c0 = slice * slen;

  bf16x8 bq[4][KT];
#pragma unroll
  for (int g = 0; g < 4; ++g)
#pragma unroll
    for (int kt = 0; kt < KT; ++kt)
      bq[g][kt] = *(const bf16x8*)(Xh + (size_t)(qb + g * 16) * CP + kt * 32 + quad * 8);

  unsigned kd0[M_L], kd1[M_L], kd2[M_L], kd3[M_L];
#pragma unroll
  for (int t = 0; t < M_L; ++t) {
    kd0[t] = 0xFFFFFFFFu; kd1[t] = 0xFFFFFFFFu;
    kd2[t] = 0xFFFFFFFFu; kd3[t] = 0xFFFFFFFFu;
  }

  const int NB = slen / 32;
  for (int bt = 0; bt < NB; ++bt) {
    const int cb = c0 + bt * 32;
    const size_t arow0 = (size_t)(cb + col) * CP + quad * 8;
    const size_t arow1 = arow0 + (size_t)16 * CP;
    unsigned nk0[8], nk1[8], nk2[8], nk3[8];
    {
      bf16x8 ah[KT];
#pragma unroll
      for (int kt = 0; kt < KT; ++kt)
        ah[kt] = *(const bf16x8*)(Xh + arow0 + kt * 32);
      f32x4 a0 = {0.f,0.f,0.f,0.f}, a1 = {0.f,0.f,0.f,0.f};
      f32x4 a2 = {0.f,0.f,0.f,0.f}, a3 = {0.f,0.f,0.f,0.f};
#pragma unroll
      for (int kt = 0; kt < KT; ++kt) {
        a0 = __builtin_amdgcn_mfma_f32_16x16x32_bf16(ah[kt], bq[0][kt], a0, 0, 0, 0);
        a1 = __builtin_amdgcn_mfma_f32_16x16x32_bf16(ah[kt], bq[1][kt], a1, 0, 0, 0);
        a2 = __builtin_amdgcn_mfma_f32_16x16x32_bf16(ah[kt], bq[2][kt], a2, 0, 0, 0);
        a3 = __builtin_amdgcn_mfma_f32_16x16x32_bf16(ah[kt], bq[3][kt], a3, 0, 0, 0);
      }
      f32x4 sc = *(const f32x4*)(sqv + cb + quad * 4);
      const unsigned lb = (unsigned)bt * 8;
#pragma unroll
      for (int r = 0; r < 4; ++r) {
        unsigned u0 = __float_as_uint(fmaf(a0[r], -2.f, sc[r]));
        unsigned u1 = __float_as_uint(fmaf(a1[r], -2.f, sc[r]));
        unsigned u2 = __float_as_uint(fmaf(a2[r], -2.f, sc[r]));
        unsigned u3 = __float_as_uint(fmaf(a3[r], -2.f, sc[r]));
        u0 ^= ((unsigned)((int)u0 >> 31)) | 0x80000000u;
        u1 ^= ((unsigned)((int)u1 >> 31)) | 0x80000000u;
        u2 ^= ((unsigned)((int)u2 >> 31)) | 0x80000000u;
        u3 ^= ((unsigned)((int)u3 >> 31)) | 0x80000000u;
        nk0[r] = (u0 & 0xFFFFFF00u) | (lb + r);
        nk1[r] = (u1 & 0xFFFFFF00u) | (lb + r);
        nk2[r] = (u2 & 0xFFFFFF00u) | (lb + r);
        nk3[r] = (u3 & 0xFFFFFF00u) | (lb + r);
      }
    }
    {
      bf16x8 ah[KT];
#pragma unroll
      for (int kt = 0; kt < KT; ++kt)
        ah[kt] = *(const bf16x8*)(Xh + arow1 + kt * 32);
      f32x4 a0 = {0.f,0.f,0.f,0.f}, a1 = {0.f,0.f,0.f,0.f};
      f32x4 a2 = {0.f,0.f,0.f,0.f}, a3 = {0.f,0.f,0.f,0.f};
#pragma unroll
      for (int kt = 0; kt < KT; ++kt) {
        a0 = __builtin_amdgcn_mfma_f32_16x16x32_bf16(ah[kt], bq[0][kt], a0, 0, 0, 0);
        a1 = __builtin_amdgcn_mfma_f32_16x16x32_bf16(ah[kt], bq[1][kt], a1, 0, 0, 0);
        a2 = __builtin_amdgcn_mfma_f32_16x16x32_bf16(ah[kt], bq[2][kt], a2, 0, 0, 0);
        a3 = __builtin_amdgcn_mfma_f32_16x16x32_bf16(ah[kt], bq[3][kt], a3, 0, 0, 0);
      }
      f32x4 sc = *(const f32x4*)(sqv + cb + 16 + quad * 4);
      const unsigned lb = (unsigned)bt * 8 + 4;
#pragma unroll
      for (int r = 0; r < 4; ++r) {
        unsigned u0 = __float_as_uint(fmaf(a0[r], -2.f, sc[r]));
        unsigned u1 = __float_as_uint(fmaf(a1[r], -2.f, sc[r]));
        unsigned u2 = __float_as_uint(fmaf(a2[r], -2.f, sc[r]));
        unsigned u3 = __float_as_uint(fmaf(a3[r], -2.f, sc[r]));
        u0 ^= ((unsigned)((int)u0 >> 31)) | 0x80000000u;
        u1 ^= ((unsigned)((int)u1 >> 31)) | 0x80000000u;
        u2 ^= ((unsigned)((int)u2 >> 31)) | 0x80000000u;
        u3 ^= ((unsigned)((int)u3 >> 31)) | 0x80000000u;
        nk0[4 + r] = (u0 & 0xFFFFFF00u) | (lb + r);
        nk1[4 + r] = (u1 & 0xFFFFFF00u) | (lb + r);
        nk2[4 + r] = (u2 & 0xFFFFFF00u) | (lb + r);
        nk3[4 + r] = (u3 & 0xFFFFFF00u) | (lb + r);
      }
    }
    SORT8(nk0) MERGE8(kd0, nk0)
    SORT8(nk1) MERGE8(kd1, nk1)
    SORT8(nk2) MERGE8(kd2, nk2)
    SORT8(nk3) MERGE8(kd3, nk3)
  }

#pragma unroll
  for (int g = 0; g < 4; ++g) {
    const unsigned* kd = (g == 0) ? kd0 : (g == 1) ? kd1 : (g == 2) ? kd2 : kd3;
    unsigned short* o =
        cand + ((size_t)(qb + g * 16) * S_SL + slice) * (4 * M_L) + quad * M_L;
#pragma unroll
    for (int t = 0; t < M_L; ++t) {
      unsigned l = kd[t] & 0xFFu;
      o[t] = (unsigned short)(c0 + (int)(l >> 2) * 16 + quad * 4 + (int)(l & 3));
    }
  }
}

// ---- pass 2 v2 (C=64): LDS-staged gather (32-cand batches) + DPP reduce ----
__global__ __launch_bounds__(256) void knn_pass2v2(
    const float* __restrict__ X, const float* __restrict__ sqv,
    const unsigned short* __restrict__ cand, int* __restrict__ knn) {
  __shared__ int   ldsC[4][CPQ];
  __shared__ float ldsD[4][CPQ];
  const int lane = threadIdx.x & 63, wv = threadIdx.x >> 6;
  const int q = blockIdx.x * 4 + wv;
  const int s = lane & 15;
  const int g = lane >> 4;
  const float sqq = sqv[q];
  constexpr int PL = CPQ / 64;   // 8

#pragma unroll
  for (int u = 0; u < PL; ++u)
    ldsC[wv][u * 64 + lane] = (int)cand[(size_t)q * CPQ + u * 64 + lane];
  f32x4 xq = *(const f32x4*)(X + (size_t)q * 64 + s * 4);
  __syncthreads();

  for (int it = 0; it < CPQ / 32; ++it) {   // 16 iters x 32 candidates
    int jj[8];
#pragma unroll
    for (int uu = 0; uu < 8; ++uu) jj[uu] = ldsC[wv][it * 32 + uu * 4 + g];
    f32x4 vv[8];
#pragma unroll
    for (int uu = 0; uu < 8; ++uu)
      vv[uu] = *(const f32x4*)(X + (size_t)jj[uu] * 64 + s * 4);
    float sj[8];
#pragma unroll
    for (int uu = 0; uu < 8; ++uu) sj[uu] = sqv[jj[uu]];
#pragma unroll
    for (int uu = 0; uu < 8; ++uu) {
      float p = fmaf(xq[0], vv[uu][0], fmaf(xq[1], vv[uu][1],
                fmaf(xq[2], vv[uu][2], xq[3] * vv[uu][3])));
      ROR_ADD(p, 8) ROR_ADD(p, 4) ROR_ADD(p, 2) ROR_ADD(p, 1)
      if (s == 0) ldsD[wv][it * 32 + uu * 4 + g] = (sqq + sj[uu]) - 2.f * p;
    }
  }
  __syncthreads();

  float d[PL]; int id[PL];
#pragma unroll
  for (int u = 0; u < PL; ++u) {
    d[u]  = ldsD[wv][u * 64 + lane];
    id[u] = ldsC[wv][u * 64 + lane];
  }
  SORTP8();
  for (int r = 0; r < KK; ++r) {
    float bd = d[0]; int bi = id[0];
#pragma unroll
    for (int off = 32; off; off >>= 1) {
      float od = __shfl_xor(bd, off, 64);
      int   oi = __shfl_xor(bi, off, 64);
      bool c = (od < bd) || (od == bd && oi < bi);
      bd = c ? od : bd; bi = c ? oi : bi;
    }
    if (lane == 0) knn[(size_t)q * KK + r] = bi;
    bool win = (d[0] == bd) && (id[0] == bi);
#pragma unroll
    for (int t = 0; t < PL - 1; ++t) {
      d[t]  = win ? d[t + 1]  : d[t];
      id[t] = win ? id[t + 1] : id[t];
    }
    d[PL - 1] = win ? __builtin_inff() : d[PL - 1];
  }
}

// ---- pass 2 (coalesced, C=3 path) ------------------------------------------
template<int C, int GRP, int LG>
__global__ __launch_bounds__(256) void knn_pass2co(
    const float* __restrict__ X, const float* __restrict__ sqv,
    const unsigned short* __restrict__ cand, int* __restrict__ knn) {
  __shared__ float ldsD[4][CPQ];
  const int lane = threadIdx.x & 63, wv = threadIdx.x >> 6;
  const int q = blockIdx.x * 4 + wv;
  const int s = lane & (GRP - 1);
  const int g = lane >> LG;
  constexpr int RPI = 64 / GRP;
  constexpr int NIT = CPQ / RPI;
  const float sqq = sqv[q];

  float xqv[4];
  if constexpr (GRP == 16) {
#pragma unroll
    for (int u = 0; u < 4; ++u) xqv[u] = X[(size_t)q * C + s * 4 + u];
  } else {
    xqv[0] = (s < C) ? X[(size_t)q * C + s] : 0.f;
  }

  for (int it = 0; it < NIT; ++it) {
    const int t = it * RPI + g;
    const int j = (int)cand[(size_t)q * CPQ + t];
    float p;
    if constexpr (GRP == 16) {
      f32x4 v = *(const f32x4*)(X + (size_t)j * C + s * 4);
      p = fmaf(xqv[0], v[0], fmaf(xqv[1], v[1], fmaf(xqv[2], v[2], xqv[3] * v[3])));
    } else {
      float v = (s < C) ? X[(size_t)j * C + s] : 0.f;
      p = xqv[0] * v;
    }
#pragma unroll
    for (int off = 1; off < GRP; off <<= 1) p += __shfl_xor(p, off, 64);
    if (s == 0) ldsD[wv][t] = (sqq + sqv[j]) - 2.f * p;
  }
  __syncthreads();

  constexpr int PL = CPQ / 64;
  float d[PL]; int id[PL];
#pragma unroll
  for (int u = 0; u < PL; ++u) {
    d[u]  = ldsD[wv][u * 64 + lane];
    id[u] = (int)cand[(size_t)q * CPQ + u * 64 + lane];
  }
  for (int r = 0; r < KK; ++r) {
    float bd = d[0]; int bi = id[0];
#pragma unroll
    for (int u = 1; u < PL; ++u) {
      bool c = (d[u] < bd) || (d[u] == bd && id[u] < bi);
      bd = c ? d[u] : bd; bi = c ? id[u] : bi;
    }
#pragma unroll
    for (int off = 32; off; off >>= 1) {
      float od = __shfl_xor(bd, off, 64);
      int   oi = __shfl_xor(bi, off, 64);
      bool c = (od < bd) || (od == bd && oi < bi);
      bd = c ? od : bd; bi = c ? oi : bi;
    }
    if (lane == 0) knn[(size_t)q * KK + r] = bi;
#pragma unroll
    for (int u = 0; u < PL; ++u) if (id[u] == bi) d[u] = __builtin_inff();
  }
}

// ---- DynamicEdgeConv with fused epilogues ----------------------------------
template<int C, int PPW, int EPI>
__global__ __launch_bounds__(256) void edge_conv(
    const float* __restrict__ X, const int* __restrict__ knn,
    const float* __restrict__ W, const float* __restrict__ B,
    float* __restrict__ Y, float* __restrict__ sqv,
    short* __restrict__ Xh, short* __restrict__ Xl) {
  const int wv = __builtin_amdgcn_readfirstlane(threadIdx.x >> 6);
  const int lane = threadIdx.x & 63;
  float wd[C], wj[C];
#pragma unroll
  for (int c = 0; c < C; ++c) {
    float w0 = W[c * 64 + lane];
    float w1 = W[(C + c) * 64 + lane];
    wd[c] = w0 - w1; wj[c] = w1;
  }
  const float bb = B[lane];
  const int p0 = (blockIdx.x * 4 + wv) * PPW;
  for (int pp = 0; pp < PPW; ++pp) {
    const int p = p0 + pp;
    const float* __restrict__ xi = X + (size_t)p * C;
    float base = bb;
#pragma unroll
    for (int c = 0; c < C; ++c) base = fmaf(xi[c], wd[c], base);
    float m = -__builtin_inff();
    for (int n = 0; n < KK; ++n) {
      const int j = __builtin_amdgcn_readfirstlane(knn[(size_t)p * KK + n]);
      const float* __restrict__ xj = X + (size_t)j * C;
      float acc;
      if constexpr (C % 4 == 0) {
        float a0 = 0.f, a1 = 0.f, a2 = 0.f, a3 = 0.f;
#pragma unroll
        for (int c = 0; c < C; c += 4) {
          a0 = fmaf(xj[c + 0], wj[c + 0], a0);
          a1 = fmaf(xj[c + 1], wj[c + 1], a1);
          a2 = fmaf(xj[c + 2], wj[c + 2], a2);
          a3 = fmaf(xj[c + 3], wj[c + 3], a3);
        }
        acc = base + ((a0 + a1) + (a2 + a3));
      } else {
        acc = base;
#pragma unroll
        for (int c = 0; c < C; ++c) acc = fmaf(xj[c], wj[c], acc);
      }
      acc = acc > 0.f ? acc : NS * acc;
      m = fmaxf(m, acc);
    }
    if constexpr (EPI == 1) {
      Y[(size_t)p * 64 + lane] = m;
      Xh[(size_t)p * 64 + lane] = f2bf_rne(m);
      float s = m * m;
#pragma unroll
      for (int off = 32; off; off >>= 1) s += __shfl_xor(s, off, 64);
      if (lane == 0) sqv[p] = s;
    } else {
      short h = f2bf_rne(m);
      float hf = __uint_as_float(((unsigned)(unsigned short)h) << 16);
      Xh[(size_t)p * 64 + lane] = h;
      Xl[(size_t)p * 64 + lane] = f2bf_rne(m - hf);
    }
  }
}

// ---- edge head via hi/lo bf16 MFMA -----------------------------------------
template<int ET>
__global__ __launch_bounds__(256) void edge_head_mfma(
    const short* __restrict__ Xh, const short* __restrict__ Xl,
    const int* __restrict__ ei,
    const short* __restrict__ whH, const short* __restrict__ whL,
    const float* __restrict__ bh1, const float* __restrict__ Wh2,
    const float* __restrict__ bh2, float* __restrict__ out) {
  const int lane = threadIdx.x & 63, wv = threadIdx.x >> 6;
  const int col = lane & 15, quad = lane >> 4;

  bf16x8 bh[4][4], bl[4][4];   // [ct][kt]
#pragma unroll
  for (int ct = 0; ct < 4; ++ct)
#pragma unroll
    for (int kt = 0; kt < 4; ++kt) {
      const size_t idx = ((size_t)(ct * 4 + kt) * 64 + lane) * 8;
      bh[ct][kt] = *(const bf16x8*)(whH + idx);
      bl[ct][kt] = *(const bf16x8*)(whL + idx);
    }
  float bb[4], w2[4];
#pragma unroll
  for (int ct = 0; ct < 4; ++ct) {
    bb[ct] = bh1[ct * 16 + col];
    w2[ct] = Wh2[ct * 16 + col];
  }
  const float b2 = bh2[0];

  const int t0 = (blockIdx.x * 4 + wv) * ET;
  for (int tt = 0; tt < ET; ++tt) {
    const int e = (t0 + tt) * 16 + col;
    const int a = ei[e], b = ei[NEDGE + e];
    const int v0 = min(a, b), v1 = max(a, b);
    bf16x8 ah[4], al[4];
#pragma unroll
    for (int kt = 0; kt < 4; ++kt) {
      const int row = (kt < 2) ? v0 : v1;
      const size_t off = (size_t)row * 64 + (kt & 1) * 32 + quad * 8;
      ah[kt] = *(const bf16x8*)(Xh + off);
      al[kt] = *(const bf16x8*)(Xl + off);
    }
    f32x4 acc[4];
#pragma unroll
    for (int ct = 0; ct < 4; ++ct) acc[ct] = f32x4{0.f, 0.f, 0.f, 0.f};
#pragma unroll
    for (int kt = 0; kt < 4; ++kt)
#pragma unroll
      for (int ct = 0; ct < 4; ++ct) {
        acc[ct] = __builtin_amdgcn_mfma_f32_16x16x32_bf16(ah[kt], bh[ct][kt], acc[ct], 0, 0, 0);
        acc[ct] = __builtin_amdgcn_mfma_f32_16x16x32_bf16(ah[kt], bl[ct][kt], acc[ct], 0, 0, 0);
        acc[ct] = __builtin_amdgcn_mfma_f32_16x16x32_bf16(al[kt], bh[ct][kt], acc[ct], 0, 0, 0);
      }
    float z[4];
#pragma unroll
    for (int r = 0; r < 4; ++r) {
      float zz = 0.f;
#pragma unroll
      for (int ct = 0; ct < 4; ++ct) {
        float h = acc[ct][r] + bb[ct];
        h = h > 0.f ? h : NS * h;
        zz = fmaf(h, w2[ct], zz);
      }
      ROR_ADD(zz, 8) ROR_ADD(zz, 4) ROR_ADD(zz, 2) ROR_ADD(zz, 1)
      z[r] = zz;
    }
    if (col == 0) {
#pragma unroll
      for (int r = 0; r < 4; ++r)
        out[(t0 + tt) * 16 + quad * 4 + r] = 1.f / (1.f + expf(-(z[r] + b2)));
    }
  }
}

// -----------------------------------------------------------------------------
extern "C" void kernel_launch(void* const* d_in, const int* in_sizes, int n_in,
                              void* d_out, int out_size, void* d_ws, size_t ws_size,
                              hipStream_t stream) {
  const float* x   = (const float*)d_in[0];
  const int*   ei  = (const int*)d_in[1];
  const float* W1  = (const float*)d_in[2];
  const float* b1  = (const float*)d_in[3];
  const float* W2  = (const float*)d_in[4];
  const float* b2  = (const float*)d_in[5];
  const float* W3  = (const float*)d_in[6];
  const float* b3  = (const float*)d_in[7];
  const float* Wh1 = (const float*)d_in[8];
  const float* bh1 = (const float*)d_in[9];
  const float* Wh2 = (const float*)d_in[10];
  const float* bh2 = (const float*)d_in[11];
  float* out = (float*)d_out;

  char* ws = (char*)d_ws;
  float* xA  = (float*)ws; ws += (size_t)N_PTS * 64 * 4;      // 4 MB
  float* xB  = (float*)ws; ws += (size_t)N_PTS * 64 * 4;      // 4 MB
  float* sqb = (float*)ws; ws += (size_t)N_PTS * 4;
  int*   knn = (int*)ws;   ws += (size_t)N_PTS * KK * 4;      // 1.9 MB
  short* Xh  = (short*)ws; ws += (size_t)N_PTS * 64 * 2;      // 2 MB
  short* Xl  = (short*)ws; ws += (size_t)N_PTS * 64 * 2;      // 2 MB
  short* whH = (short*)ws; ws += (size_t)8192 * 2;            // 16 KB
  short* whL = (short*)ws; ws += (size_t)8192 * 2;            // 16 KB
  unsigned short* cand = (unsigned short*)ws;
  ws += (size_t)N_PTS * CPQ * 2;                              // 16.7 MB
  (void)ws_size; (void)in_sizes; (void)n_in; (void)out_size;

  wh1prep<<<1, 256, 0, stream>>>(Wh1, whH, whL);

  // ---- conv1 (C=3): direct fp32 scan; edge_conv fuses sq+bf16hi of xA ----
  sq3<<<N_PTS / 256, 256, 0, stream>>>(x, sqb);
  knn_scan3<<<dim3(N_PTS / 256, S_SL), 256, 0, stream>>>(x, sqb, cand);
  knn_pass2co<3, 4, 2><<<N_PTS / 4, 256, 0, stream>>>(x, sqb, cand, knn);
  edge_conv<3, 4, 1><<<N_PTS / 16, 256, 0, stream>>>(x, knn, W1, b1, xA, sqb, Xh, Xl);
  // ---- conv2 (C=64): edge_conv fuses sq+bf16hi of xB ----
  knn_pass1<2><<<dim3(N_PTS / 256, S_SL), 256, 0, stream>>>(Xh, sqb, cand);
  knn_pass2v2<<<N_PTS / 4, 256, 0, stream>>>(xA, sqb, cand, knn);
  edge_conv<64, 4, 1><<<N_PTS / 16, 256, 0, stream>>>(xA, knn, W2, b2, xB, sqb, Xh, Xl);
  // ---- conv3 (C=64): edge_conv emits hi/lo planes only (no Y) ----
  knn_pass1<2><<<dim3(N_PTS / 256, S_SL), 256, 0, stream>>>(Xh, sqb, cand);
  knn_pass2v2<<<N_PTS / 4, 256, 0, stream>>>(xB, sqb, cand, knn);
  edge_conv<64, 4, 2><<<N_PTS / 16, 256, 0, stream>>>(xB, knn, W3, b3, nullptr, nullptr, Xh, Xl);
  // ---- edge head: MFMA on hi/lo planes ----
  edge_head_mfma<8><<<NEDGE / (16 * 4 * 8), 256, 0, stream>>>(
      Xh, Xl, ei, whH, whL, bh1, Wh2, bh2, out);
}